// Round 5
// baseline (843.980 us; speedup 1.0000x reference)
//
#include <hip/hip_runtime.h>
#include <hip/hip_bf16.h>

typedef __bf16 bf16_t;
typedef bf16_t bf16x8 __attribute__((ext_vector_type(8)));
typedef float f32x4 __attribute__((ext_vector_type(4)));

__device__ __forceinline__ float bflo(unsigned int p){ union{unsigned int u; float f;} c; c.u = p << 16; return c.f; }
__device__ __forceinline__ float bfhi(unsigned int p){ union{unsigned int u; float f;} c; c.u = p & 0xffff0000u; return c.f; }
__device__ __forceinline__ unsigned int f2bfu(float f){
  union{float f; unsigned int u;} c; c.f = f;
  return (c.u + 0x7fffu + ((c.u >> 16) & 1u)) >> 16;
}

// ---------------- cast x (f32 -> bf16 pairs), float4 loads ----------------
__global__ void k_cast_x(const float4* __restrict__ x, uint2* __restrict__ xb, int nq){
  int stride = gridDim.x * blockDim.x;
  for (int i = blockIdx.x * blockDim.x + threadIdx.x; i < nq; i += stride){
    float4 v = x[i];
    uint2 o;
    o.x = f2bfu(v.x) | (f2bfu(v.y) << 16);
    o.y = f2bfu(v.z) | (f2bfu(v.w) << 16);
    xb[i] = o;
  }
}

// ---------------- cast + transpose 4 weights in one launch ----------------
__global__ void k_castT_w4(const float* __restrict__ W0, const float* __restrict__ W1,
                           const float* __restrict__ W2, const float* __restrict__ W3,
                           unsigned short* __restrict__ T0, unsigned short* __restrict__ T1,
                           unsigned short* __restrict__ T2, unsigned short* __restrict__ T3){
  const float* W; unsigned short* T;
  switch (blockIdx.y){
    case 0: W = W0; T = T0; break;
    case 1: W = W1; T = T1; break;
    case 2: W = W2; T = T2; break;
    default: W = W3; T = T3; break;
  }
  int idx = blockIdx.x * 256 + threadIdx.x;
  int k = idx / 384, n = idx - k * 384;
  T[n * 384 + k] = (unsigned short)f2bfu(W[idx]);
}

// ---------------- degree count ----------------
__global__ void k_deg(const int* __restrict__ dst, int* __restrict__ deg, int E){
  int stride = gridDim.x * blockDim.x;
  for (int e = blockIdx.x * blockDim.x + threadIdx.x; e < E; e += stride)
    atomicAdd(&deg[dst[e]], 1);
}

// ---------------- parallel scan, 3 kernels ----------------
__global__ void k_scan1(const int* __restrict__ deg, int* __restrict__ incl,
                        int* __restrict__ bsum, int n){
  __shared__ int wsum[16];
  int t = threadIdx.x, l = t & 63, w = t >> 6;
  int i = blockIdx.x * 1024 + t;
  int v = (i < n) ? deg[i] : 0;
  int xv = v;
  #pragma unroll
  for (int s = 1; s < 64; s <<= 1){
    int y = __shfl_up(xv, s, 64);
    if (l >= s) xv += y;
  }
  if (l == 63) wsum[w] = xv;
  __syncthreads();
  int off = 0;
  for (int k2 = 0; k2 < w; ++k2) off += wsum[k2];
  if (i < n) incl[i] = off + xv;
  if (t == 0){
    int tot = 0;
    for (int k2 = 0; k2 < 16; ++k2) tot += wsum[k2];
    bsum[blockIdx.x] = tot;
  }
}

__global__ void k_scan2(int* __restrict__ bsum, int nb){
  __shared__ int wtot;
  int t = threadIdx.x, l = t & 63, w = t >> 6;
  int v = (t < nb) ? bsum[t] : 0;
  int xv = v;
  #pragma unroll
  for (int s = 1; s < 64; s <<= 1){
    int y = __shfl_up(xv, s, 64);
    if (l >= s) xv += y;
  }
  if (t == 63) wtot = xv;
  __syncthreads();
  int off = (w == 1) ? wtot : 0;
  if (t < nb) bsum[t] = off + xv - v;
}

__global__ void k_scan3(const int* __restrict__ incl, const int* __restrict__ bsum,
                        const int* __restrict__ deg, int* __restrict__ rowptr,
                        int* __restrict__ cursor, int n){
  int i = blockIdx.x * 256 + threadIdx.x;
  if (i < n){
    int r = incl[i] + bsum[i >> 10];
    rowptr[i + 1] = r;
    cursor[i] = r - deg[i];
  }
  if (i == 0) rowptr[0] = 0;
}

// ---------------- CSR fill: packed {src, weight_bits} ----------------
__global__ void k_fill(const int* __restrict__ src, const int* __restrict__ dst, const float* __restrict__ ew,
                       int* __restrict__ cursor, int2* __restrict__ csr, int E){
  int stride = gridDim.x * blockDim.x;
  for (int e = blockIdx.x * blockDim.x + threadIdx.x; e < E; e += stride){
    int d = dst[e];
    int pos = atomicAdd(&cursor[d], 1);
    int2 c; c.x = src[e]; c.y = __float_as_int(ew[e]);
    csr[pos] = c;
  }
}

// ---------------- mean aggregation: one wave per node, 2x unrolled ----------------
__global__ void k_agg(const unsigned short* __restrict__ X, unsigned short* __restrict__ OUT,
                      const int* __restrict__ rowptr, const int2* __restrict__ csr, int n_nodes){
  int w = threadIdx.x >> 6, l = threadIdx.x & 63;
  int node = blockIdx.x * 4 + w;
  if (node >= n_nodes) return;
  int e0 = rowptr[node], e1 = rowptr[node + 1];
  float a0=0,a1=0,a2=0,a3=0,a4=0,a5=0;
  const unsigned int* X32 = (const unsigned int*)X;
  int e = e0;
  for (; e + 2 <= e1; e += 2){
    int2 c0 = csr[e], c1 = csr[e + 1];
    const unsigned int* x0 = X32 + (long)c0.x * 192;
    const unsigned int* x1 = X32 + (long)c1.x * 192;
    unsigned int p0 = x0[l], p1 = x0[l + 64], p2 = x0[l + 128];
    unsigned int q0 = x1[l], q1 = x1[l + 64], q2 = x1[l + 128];
    float w0 = __int_as_float(c0.y), w1 = __int_as_float(c1.y);
    a0 += w0 * bflo(p0); a1 += w0 * bfhi(p0);
    a2 += w0 * bflo(p1); a3 += w0 * bfhi(p1);
    a4 += w0 * bflo(p2); a5 += w0 * bfhi(p2);
    a0 += w1 * bflo(q0); a1 += w1 * bfhi(q0);
    a2 += w1 * bflo(q1); a3 += w1 * bfhi(q1);
    a4 += w1 * bflo(q2); a5 += w1 * bfhi(q2);
  }
  if (e < e1){
    int2 c0 = csr[e];
    const unsigned int* x0 = X32 + (long)c0.x * 192;
    unsigned int p0 = x0[l], p1 = x0[l + 64], p2 = x0[l + 128];
    float w0 = __int_as_float(c0.y);
    a0 += w0 * bflo(p0); a1 += w0 * bfhi(p0);
    a2 += w0 * bflo(p1); a3 += w0 * bfhi(p1);
    a4 += w0 * bflo(p2); a5 += w0 * bfhi(p2);
  }
  int degn = e1 - e0;
  float inv = 1.0f / (float)(degn > 1 ? degn : 1);
  unsigned int* O32 = (unsigned int*)OUT + (long)node * 192;
  O32[l]       = f2bfu(a0 * inv) | (f2bfu(a1 * inv) << 16);
  O32[l + 64]  = f2bfu(a2 * inv) | (f2bfu(a3 * inv) << 16);
  O32[l + 128] = f2bfu(a4 * inv) | (f2bfu(a5 * inv) << 16);
}

// ---------------- fused dual GEMM: barrier-free, LDS-free, all-register ----------------
// C = relu(A1@B1^T + bias + A2@B2^T). A [NN,384] bf16 row-major; B = WT [384n][384k] bf16.
// Block = 128x128 tile, 4 waves in 2x2; each wave computes 64x64 entirely in registers.
// A fragments prefetched one full K-step (BK=64) ahead; B fragments one half-step ahead.
// No __syncthreads / s_barrier / vmcnt(0) in the main loop -> waves slip freely.
template<int OUT_BF16>
__global__ __launch_bounds__(256) void k_gemm(
    const unsigned short* __restrict__ A1, const unsigned short* __restrict__ B1,
    const unsigned short* __restrict__ A2, const unsigned short* __restrict__ B2,
    const float* __restrict__ bias, void* __restrict__ Cout,
    const float* __restrict__ WL, float* __restrict__ olog,
    int NN, int q, int r)
{
  __shared__ __align__(16) unsigned short lsE[OUT_BF16 ? 128 * 128 : 64];
  int t = threadIdx.x;
  int w = t >> 6, l = t & 63;

  // bijective XCD swizzle (m204)
  int lin = blockIdx.x;
  int xcd = lin & 7, idx = lin >> 3;
  int nl = idx + ((xcd < r) ? xcd * (q + 1) : r * (q + 1) + (xcd - r) * q);
  int mt = nl / 3, nt = nl - mt * 3;
  int m0 = mt * 128, n0 = nt * 128;
  int wrow = (w & 1) * 64, wcol = (w >> 1) * 64;

  int colb = l & 15, kq = l >> 4;   // fragment row lane / k-chunk lane

  f32x4 acc[4][4] = {};

  // per-lane fragment pointers; kq*8 k-offset folded in, rest is compile-time immediate
  const unsigned short* pA[4];
  const unsigned short* pB[4];
  #pragma unroll
  for (int mi = 0; mi < 4; ++mi){
    int rA = m0 + wrow + mi * 16 + colb; if (rA >= NN) rA = NN - 1;
    pA[mi] = A1 + (long)rA * 384 + kq * 8;
  }
  #pragma unroll
  for (int ni = 0; ni < 4; ++ni){
    int rB = n0 + wcol + ni * 16 + colb;
    pB[ni] = B1 + (long)rB * 384 + kq * 8;
  }
  const long dA = A2 - A1, dB = B2 - B1;

  bf16x8 afb[2][2][4];   // [buf][s][mi] — full-step double buffer
  bf16x8 bfb[2][4];      // [s-parity][ni] — half-step double buffer

  // prologue: step-0 A (both halves), sub-step-0 B
  #pragma unroll
  for (int s = 0; s < 2; ++s)
    #pragma unroll
    for (int mi = 0; mi < 4; ++mi)
      afb[0][s][mi] = *(const bf16x8*)(pA[mi] + s * 32);
  #pragma unroll
  for (int ni = 0; ni < 4; ++ni)
    bfb[0][ni] = *(const bf16x8*)(pB[ni]);

  #pragma unroll
  for (int kk = 0; kk < 12; ++kk){
    const int cur = kk & 1;
    const int kc  = (kk < 6 ? kk : kk - 6) * 64;

    // ---- s = 0 ----
    if (kk == 5){
      #pragma unroll
      for (int mi = 0; mi < 4; ++mi) pA[mi] += dA;   // switch to A2 before prefetching step 6
    }
    if (kk < 11){
      const int kc2 = ((kk + 1) < 6 ? (kk + 1) : (kk + 1) - 6) * 64;
      #pragma unroll
      for (int s = 0; s < 2; ++s)
        #pragma unroll
        for (int mi = 0; mi < 4; ++mi)
          afb[cur ^ 1][s][mi] = *(const bf16x8*)(pA[mi] + kc2 + s * 32);
    }
    #pragma unroll
    for (int ni = 0; ni < 4; ++ni)                    // B for (kk, s=1)
      bfb[1][ni] = *(const bf16x8*)(pB[ni] + kc + 32);
    #pragma unroll
    for (int mi = 0; mi < 4; ++mi)
      #pragma unroll
      for (int ni = 0; ni < 4; ++ni)
        acc[mi][ni] = __builtin_amdgcn_mfma_f32_16x16x32_bf16(afb[cur][0][mi], bfb[0][ni], acc[mi][ni], 0, 0, 0);

    // ---- s = 1 ----
    if (kk == 5){
      #pragma unroll
      for (int ni = 0; ni < 4; ++ni) pB[ni] += dB;   // switch to B2 before prefetching step 6
    }
    if (kk < 11){
      const int kc2 = ((kk + 1) < 6 ? (kk + 1) : (kk + 1) - 6) * 64;
      #pragma unroll
      for (int ni = 0; ni < 4; ++ni)                  // B for (kk+1, s=0)
        bfb[0][ni] = *(const bf16x8*)(pB[ni] + kc2);
    }
    #pragma unroll
    for (int mi = 0; mi < 4; ++mi)
      #pragma unroll
      for (int ni = 0; ni < 4; ++ni)
        acc[mi][ni] = __builtin_amdgcn_mfma_f32_16x16x32_bf16(afb[cur][1][mi], bfb[1][ni], acc[mi][ni], 0, 0, 0);
  }

  // ---------------- epilogue ----------------
  if (OUT_BF16){
    // repack through LDS -> fully coalesced 16B bf16 stores
    __syncthreads();
    #pragma unroll
    for (int mi = 0; mi < 4; ++mi)
      #pragma unroll
      for (int ni = 0; ni < 4; ++ni){
        f32x4 v = acc[mi][ni];
        int col = wcol + ni * 16 + colb;
        float bcol = bias[n0 + col];
        #pragma unroll
        for (int rr = 0; rr < 4; ++rr){
          int row = wrow + mi * 16 + kq * 4 + rr;
          lsE[row * 128 + col] = (unsigned short)f2bfu(fmaxf(v[rr] + bcol, 0.0f));
        }
      }
    __syncthreads();
    unsigned short* Cb = (unsigned short*)Cout;
    #pragma unroll
    for (int p = 0; p < 8; ++p){
      int idx16 = p * 256 + t;
      int row = idx16 >> 4, chunk = idx16 & 15;
      int rg = m0 + row;
      if (rg < NN)
        *(uint4*)((char*)Cb + (long)rg * 768 + n0 * 2 + chunk * 16) =
            *(const uint4*)((const char*)lsE + idx16 * 16);
    }
  } else {
    float* Cf = (float*)Cout;
    #pragma unroll
    for (int mi = 0; mi < 4; ++mi){
      float po[4][2] = {};
      #pragma unroll
      for (int ni = 0; ni < 4; ++ni){
        f32x4 v = acc[mi][ni];
        int col = n0 + wcol + ni * 16 + colb;
        float bcol = bias[col];
        float w0 = WL[col * 2], w1 = WL[col * 2 + 1];
        #pragma unroll
        for (int rr = 0; rr < 4; ++rr){
          int row = m0 + wrow + mi * 16 + kq * 4 + rr;
          float val = fmaxf(v[rr] + bcol, 0.0f);
          if (row < NN) Cf[(long)row * 384 + col] = val;
          po[rr][0] += val * w0;
          po[rr][1] += val * w1;
        }
      }
      #pragma unroll
      for (int rr = 0; rr < 4; ++rr)
        #pragma unroll
        for (int o = 0; o < 2; ++o){
          float v = po[rr][o];
          v += __shfl_xor(v, 1); v += __shfl_xor(v, 2);
          v += __shfl_xor(v, 4); v += __shfl_xor(v, 8);
          int row = m0 + wrow + mi * 16 + kq * 4 + rr;
          if (colb == 0 && row < NN) atomicAdd(&olog[row * 2 + o], v);
        }
    }
  }
}

// ---------------- sigmoid(olog + b) ----------------
__global__ void k_sig(const float* __restrict__ olog, const float* __restrict__ bl,
                      float* __restrict__ out, int n2){
  int i = blockIdx.x * 256 + threadIdx.x;
  if (i < n2) out[i] = 1.f / (1.f + expf(-(olog[i] + bl[i & 1])));
}

extern "C" void kernel_launch(void* const* d_in, const int* in_sizes, int n_in,
                              void* d_out, int out_size, void* d_ws, size_t ws_size,
                              hipStream_t stream) {
  const float* x      = (const float*)d_in[0];
  const int*   ei     = (const int*)d_in[1];
  const float* ew     = (const float*)d_in[2];
  const float* Wrel1  = (const float*)d_in[3];
  const float* brel1  = (const float*)d_in[4];
  const float* Wroot1 = (const float*)d_in[5];
  const float* Wrel2  = (const float*)d_in[6];
  const float* brel2  = (const float*)d_in[7];
  const float* Wroot2 = (const float*)d_in[8];
  const float* Wlin   = (const float*)d_in[9];
  const float* blin   = (const float*)d_in[10];

  const int NN = in_sizes[0] / 384;
  const int E  = in_sizes[2];
  const int* src = ei;
  const int* dst = ei + E;

  char* p = (char*)d_ws;
  auto carve = [&](size_t bytes) -> void* {
    void* r = (void*)p;
    p += (bytes + 255) & ~(size_t)255;
    return r;
  };
  int*   deg     = (int*)carve((size_t)NN * 4);
  int*   rowptr  = (int*)carve((size_t)(NN + 1) * 4);
  int*   cursor  = (int*)carve((size_t)NN * 4);
  int*   incl    = (int*)carve((size_t)NN * 4);
  int*   bsum    = (int*)carve(1024);
  float* olog    = (float*)carve((size_t)NN * 2 * 4);
  int2*  csr     = (int2*)carve((size_t)E * 8);
  unsigned short* xb  = (unsigned short*)carve((size_t)NN * 384 * 2);
  unsigned short* m1b = (unsigned short*)carve((size_t)NN * 384 * 2);
  unsigned short* hb  = (unsigned short*)carve((size_t)NN * 384 * 2);
  unsigned short* WT1 = (unsigned short*)carve(384 * 384 * 2);
  unsigned short* WT2 = (unsigned short*)carve(384 * 384 * 2);
  unsigned short* WT3 = (unsigned short*)carve(384 * 384 * 2);
  unsigned short* WT4 = (unsigned short*)carve(384 * 384 * 2);

  float* out = (float*)d_out;
  float* Y   = out + (size_t)NN * 2;

  int nScanB = (NN + 1023) / 1024;

  hipMemsetAsync(deg, 0, (size_t)NN * 4, stream);
  hipMemsetAsync(olog, 0, (size_t)NN * 8, stream);
  k_cast_x<<<2048, 256, 0, stream>>>((const float4*)x, (uint2*)xb, NN * 96);
  dim3 wg(576, 4);
  k_castT_w4<<<wg, 256, 0, stream>>>(Wrel1, Wroot1, Wrel2, Wroot2, WT1, WT2, WT3, WT4);
  k_deg<<<1024, 256, 0, stream>>>(dst, deg, E);
  k_scan1<<<nScanB, 1024, 0, stream>>>(deg, incl, bsum, NN);
  k_scan2<<<1, 128, 0, stream>>>(bsum, nScanB);
  k_scan3<<<(NN + 255) / 256, 256, 0, stream>>>(incl, bsum, deg, rowptr, cursor, NN);
  k_fill<<<1024, 256, 0, stream>>>(src, dst, ew, cursor, csr, E);

  int aggBlocks = (NN + 3) / 4;
  k_agg<<<aggBlocks, 256, 0, stream>>>(xb, m1b, rowptr, csr, NN);

  int nwg = 3 * ((NN + 127) / 128);
  int q = nwg >> 3, r = nwg & 7;
  k_gemm<1><<<nwg, 256, 0, stream>>>(m1b, WT1, xb, WT2, brel1, (void*)hb,
                                     nullptr, nullptr, NN, q, r);

  k_agg<<<aggBlocks, 256, 0, stream>>>(hb, m1b, rowptr, csr, NN);

  k_gemm<0><<<nwg, 256, 0, stream>>>(m1b, WT3, hb, WT4, brel2, (void*)Y,
                                     Wlin, olog, NN, q, r);

  k_sig<<<(NN * 2 + 255) / 256, 256, 0, stream>>>(olog, blin, out, NN * 2);
}

// Round 7
// 649.463 us; speedup vs baseline: 1.2995x; 1.2995x over previous
//
#include <hip/hip_runtime.h>
#include <hip/hip_bf16.h>

typedef __bf16 bf16_t;
typedef bf16_t bf16x8 __attribute__((ext_vector_type(8)));
typedef float f32x4 __attribute__((ext_vector_type(4)));

typedef __attribute__((address_space(3))) unsigned int lds_u32;
typedef __attribute__((address_space(1))) unsigned int glb_u32;

__device__ __forceinline__ float bflo(unsigned int p){ union{unsigned int u; float f;} c; c.u = p << 16; return c.f; }
__device__ __forceinline__ float bfhi(unsigned int p){ union{unsigned int u; float f;} c; c.u = p & 0xffff0000u; return c.f; }
__device__ __forceinline__ unsigned int f2bfu(float f){
  union{float f; unsigned int u;} c; c.f = f;
  return (c.u + 0x7fffu + ((c.u >> 16) & 1u)) >> 16;
}

// ---------------- cast x (f32 -> bf16 pairs), float4 loads ----------------
__global__ void k_cast_x(const float4* __restrict__ x, uint2* __restrict__ xb, int nq){
  int stride = gridDim.x * blockDim.x;
  for (int i = blockIdx.x * blockDim.x + threadIdx.x; i < nq; i += stride){
    float4 v = x[i];
    uint2 o;
    o.x = f2bfu(v.x) | (f2bfu(v.y) << 16);
    o.y = f2bfu(v.z) | (f2bfu(v.w) << 16);
    xb[i] = o;
  }
}

// ---------------- cast + transpose 4 weights in one launch ----------------
__global__ void k_castT_w4(const float* __restrict__ W0, const float* __restrict__ W1,
                           const float* __restrict__ W2, const float* __restrict__ W3,
                           unsigned short* __restrict__ T0, unsigned short* __restrict__ T1,
                           unsigned short* __restrict__ T2, unsigned short* __restrict__ T3){
  const float* W; unsigned short* T;
  switch (blockIdx.y){
    case 0: W = W0; T = T0; break;
    case 1: W = W1; T = T1; break;
    case 2: W = W2; T = T2; break;
    default: W = W3; T = T3; break;
  }
  int idx = blockIdx.x * 256 + threadIdx.x;
  int k = idx / 384, n = idx - k * 384;
  T[n * 384 + k] = (unsigned short)f2bfu(W[idx]);
}

// ---------------- degree count ----------------
__global__ void k_deg(const int* __restrict__ dst, int* __restrict__ deg, int E){
  int stride = gridDim.x * blockDim.x;
  for (int e = blockIdx.x * blockDim.x + threadIdx.x; e < E; e += stride)
    atomicAdd(&deg[dst[e]], 1);
}

// ---------------- parallel scan, 3 kernels ----------------
__global__ void k_scan1(const int* __restrict__ deg, int* __restrict__ incl,
                        int* __restrict__ bsum, int n){
  __shared__ int wsum[16];
  int t = threadIdx.x, l = t & 63, w = t >> 6;
  int i = blockIdx.x * 1024 + t;
  int v = (i < n) ? deg[i] : 0;
  int xv = v;
  #pragma unroll
  for (int s = 1; s < 64; s <<= 1){
    int y = __shfl_up(xv, s, 64);
    if (l >= s) xv += y;
  }
  if (l == 63) wsum[w] = xv;
  __syncthreads();
  int off = 0;
  for (int k2 = 0; k2 < w; ++k2) off += wsum[k2];
  if (i < n) incl[i] = off + xv;
  if (t == 0){
    int tot = 0;
    for (int k2 = 0; k2 < 16; ++k2) tot += wsum[k2];
    bsum[blockIdx.x] = tot;
  }
}

__global__ void k_scan2(int* __restrict__ bsum, int nb){
  __shared__ int wtot;
  int t = threadIdx.x, l = t & 63, w = t >> 6;
  int v = (t < nb) ? bsum[t] : 0;
  int xv = v;
  #pragma unroll
  for (int s = 1; s < 64; s <<= 1){
    int y = __shfl_up(xv, s, 64);
    if (l >= s) xv += y;
  }
  if (t == 63) wtot = xv;
  __syncthreads();
  int off = (w == 1) ? wtot : 0;
  if (t < nb) bsum[t] = off + xv - v;
}

__global__ void k_scan3(const int* __restrict__ incl, const int* __restrict__ bsum,
                        const int* __restrict__ deg, int* __restrict__ rowptr,
                        int* __restrict__ cursor, int n){
  int i = blockIdx.x * 256 + threadIdx.x;
  if (i < n){
    int r = incl[i] + bsum[i >> 10];
    rowptr[i + 1] = r;
    cursor[i] = r - deg[i];
  }
  if (i == 0) rowptr[0] = 0;
}

// ---------------- CSR fill: packed {src, weight_bits} ----------------
__global__ void k_fill(const int* __restrict__ src, const int* __restrict__ dst, const float* __restrict__ ew,
                       int* __restrict__ cursor, int2* __restrict__ csr, int E){
  int stride = gridDim.x * blockDim.x;
  for (int e = blockIdx.x * blockDim.x + threadIdx.x; e < E; e += stride){
    int d = dst[e];
    int pos = atomicAdd(&cursor[d], 1);
    int2 c; c.x = src[e]; c.y = __float_as_int(ew[e]);
    csr[pos] = c;
  }
}

// ---------------- dual-output GEMM: P = A@B1^T, R = A@B2^T (bf16 out) ----------------
// A [NN,384] bf16 row-major; B1,B2 = WT [384n][384k] bf16 (pre-transposed).
// BM=128, BN=128, BK=32, 12 K-steps. A+B1 double-buffered in LDS via swizzled
// global_load_lds; B2 fragments global->reg, prefetched one step ahead.
// RACE-FREE ordering (T3-minimum): prefetch issued at iteration TOP, one
// __syncthreads at iteration END (vmcnt0+lgkm0 publishes next buf AND proves all
// reads of the buffer being overwritten next iter have completed).
__global__ __launch_bounds__(256) void k_gemm_dual(
    const unsigned short* __restrict__ A, const unsigned short* __restrict__ B1,
    const unsigned short* __restrict__ B2,
    unsigned short* __restrict__ P, unsigned short* __restrict__ R,
    int NN, int q, int r)
{
  // [0,16KB): A dbuf (2x8KB). [16KB,32KB): B1 dbuf. Epilogue reuses all 32KB.
  __shared__ __align__(16) unsigned short lds[2 * 128 * 32 * 2];
  int t = threadIdx.x, w = t >> 6, l = t & 63;

  // bijective XCD swizzle (m204)
  int lin = blockIdx.x, xcd = lin & 7, idx = lin >> 3;
  int nl = idx + ((xcd < r) ? xcd * (q + 1) : r * (q + 1) + (xcd - r) * q);
  int mt = nl / 3, nt = nl - mt * 3;
  int m0 = mt * 128, n0 = nt * 128;
  int wrow = (w & 1) * 64, wcol = (w >> 1) * 64;
  int colb = l & 15, kq = l >> 4;

  f32x4 accP[4][4] = {}, accR[4][4] = {};

  // stage: LDS chunk c=(q2*4+w)*64+l -> row=seg*16+(l>>2), pos=l&3.
  // stored global chunk = pos ^ ((row>>1)&3) = (l&3) ^ ((l>>3)&3)  (2-way max conflict)
  int gchunk = (l & 3) ^ ((l >> 3) & 3);

  const unsigned short* pB2[4];
  #pragma unroll
  for (int ni = 0; ni < 4; ++ni)
    pB2[ni] = B2 + (long)(n0 + wcol + ni * 16 + colb) * 384 + kq * 8;

  bf16x8 b2r[2][4];

#define STAGE(buf, kk_) do { \
    int kc_ = (kk_) * 32; \
    _Pragma("unroll") \
    for (int q2 = 0; q2 < 2; ++q2){ \
      int rt = (q2 * 4 + w) * 16 + (l >> 2); \
      int ra = m0 + rt; if (ra >= NN) ra = NN - 1; \
      __builtin_amdgcn_global_load_lds((glb_u32*)(A + (long)ra * 384 + kc_ + gchunk * 8), \
          (lds_u32*)((char*)lds + (buf) * 8192 + (q2 * 4 + w) * 1024), 16, 0, 0); \
      __builtin_amdgcn_global_load_lds((glb_u32*)(B1 + (long)(n0 + rt) * 384 + kc_ + gchunk * 8), \
          (lds_u32*)((char*)lds + 16384 + (buf) * 8192 + (q2 * 4 + w) * 1024), 16, 0, 0); \
    } \
  } while (0)

  // prologue: step-0 A/B1 into buf0, step-0 B2 into regs, publish
  STAGE(0, 0);
  #pragma unroll
  for (int ni = 0; ni < 4; ++ni)
    b2r[0][ni] = *(const bf16x8*)(pB2[ni]);
  __syncthreads();

  #pragma unroll
  for (int kk = 0; kk < 12; ++kk){
    const int cur = kk & 1;

    // prefetch next step FIRST — flies under the ds_read+MFMA phase below,
    // drained by the end-of-iter __syncthreads (full window to land)
    if (kk < 11){
      #pragma unroll
      for (int ni = 0; ni < 4; ++ni)
        b2r[cur ^ 1][ni] = *(const bf16x8*)(pB2[ni] + (kk + 1) * 32);
      STAGE(cur ^ 1, kk + 1);
    }

    const char* bA = (const char*)lds + cur * 8192;
    const char* bB = (const char*)lds + 16384 + cur * 8192;
    bf16x8 af[4], b1f[4];
    #pragma unroll
    for (int mi = 0; mi < 4; ++mi){
      int rA = wrow + mi * 16 + colb;
      af[mi] = *(const bf16x8*)(bA + rA * 64 + ((kq ^ ((rA >> 1) & 3)) << 4));
    }
    #pragma unroll
    for (int ni = 0; ni < 4; ++ni){
      int rB = wcol + ni * 16 + colb;
      b1f[ni] = *(const bf16x8*)(bB + rB * 64 + ((kq ^ ((rB >> 1) & 3)) << 4));
    }
    #pragma unroll
    for (int mi = 0; mi < 4; ++mi)
      #pragma unroll
      for (int ni = 0; ni < 4; ++ni){
        accP[mi][ni] = __builtin_amdgcn_mfma_f32_16x16x32_bf16(af[mi], b1f[ni], accP[mi][ni], 0, 0, 0);
        accR[mi][ni] = __builtin_amdgcn_mfma_f32_16x16x32_bf16(af[mi], b2r[cur][ni], accR[mi][ni], 0, 0, 0);
      }

    __syncthreads();   // vmcnt(0)+lgkmcnt(0)+barrier: next buf ready, reads done
  }
#undef STAGE

  // ---------------- epilogue: repack both tiles through LDS (32KB) ----------------
  unsigned short* lr = (unsigned short*)lds;
  #pragma unroll
  for (int pass = 0; pass < 2; ++pass){
    __syncthreads();
    #pragma unroll
    for (int mi = 0; mi < 4; ++mi)
      #pragma unroll
      for (int ni = 0; ni < 4; ++ni){
        f32x4 v = pass ? accR[mi][ni] : accP[mi][ni];
        int col = wcol + ni * 16 + colb;
        #pragma unroll
        for (int rr = 0; rr < 4; ++rr){
          int row = wrow + mi * 16 + kq * 4 + rr;
          lr[row * 128 + col] = (unsigned short)f2bfu(v[rr]);
        }
      }
    __syncthreads();
    unsigned short* O = pass ? R : P;
    #pragma unroll
    for (int p = 0; p < 8; ++p){
      int idx16 = p * 256 + t;
      int row = idx16 >> 4, chunk = idx16 & 15;
      int rg = m0 + row;
      if (rg < NN)
        *(uint4*)(O + (long)rg * 384 + n0 + chunk * 8) =
            *(const uint4*)((const char*)lds + idx16 * 16);
    }
  }
}

// ---------------- fused aggregation: h = relu(mean_gather(P) + R + b) ----------------
// FINAL=0: write bf16 h. FINAL=1: write f32 Y AND out = sigmoid(y@WL + bl) in-wave.
template<int FINAL>
__global__ void k_agg2(const unsigned short* __restrict__ Pm, const unsigned short* __restrict__ Rm,
                       const float* __restrict__ bias,
                       const int* __restrict__ rowptr, const int2* __restrict__ csr,
                       unsigned short* __restrict__ hout,
                       float* __restrict__ Y, const float* __restrict__ WL,
                       const float* __restrict__ bl, float* __restrict__ outp,
                       int n_nodes){
  int w = threadIdx.x >> 6, l = threadIdx.x & 63;
  int node = blockIdx.x * 4 + w;
  if (node >= n_nodes) return;
  int e0 = rowptr[node], e1 = rowptr[node + 1];
  float a0=0,a1=0,a2=0,a3=0,a4=0,a5=0;
  const unsigned int* P32 = (const unsigned int*)Pm;
  int e = e0;
  for (; e + 2 <= e1; e += 2){
    int2 c0 = csr[e], c1 = csr[e + 1];
    const unsigned int* x0 = P32 + (long)c0.x * 192;
    const unsigned int* x1 = P32 + (long)c1.x * 192;
    unsigned int p0 = x0[l], p1 = x0[l + 64], p2 = x0[l + 128];
    unsigned int q0 = x1[l], q1 = x1[l + 64], q2 = x1[l + 128];
    float w0 = __int_as_float(c0.y), w1 = __int_as_float(c1.y);
    a0 += w0 * bflo(p0); a1 += w0 * bfhi(p0);
    a2 += w0 * bflo(p1); a3 += w0 * bfhi(p1);
    a4 += w0 * bflo(p2); a5 += w0 * bfhi(p2);
    a0 += w1 * bflo(q0); a1 += w1 * bfhi(q0);
    a2 += w1 * bflo(q1); a3 += w1 * bfhi(q1);
    a4 += w1 * bflo(q2); a5 += w1 * bfhi(q2);
  }
  if (e < e1){
    int2 c0 = csr[e];
    const unsigned int* x0 = P32 + (long)c0.x * 192;
    unsigned int p0 = x0[l], p1 = x0[l + 64], p2 = x0[l + 128];
    float w0 = __int_as_float(c0.y);
    a0 += w0 * bflo(p0); a1 += w0 * bfhi(p0);
    a2 += w0 * bflo(p1); a3 += w0 * bfhi(p1);
    a4 += w0 * bflo(p2); a5 += w0 * bfhi(p2);
  }
  int degn = e1 - e0;
  float inv = 1.0f / (float)(degn > 1 ? degn : 1);

  const unsigned int* R32 = (const unsigned int*)Rm + (long)node * 192;
  unsigned int r0 = R32[l], r1 = R32[l + 64], r2 = R32[l + 128];
  const float2* bias2 = (const float2*)bias;
  float2 b0 = bias2[l], b1 = bias2[l + 64], b2 = bias2[l + 128];

  float h0 = fmaxf(a0 * inv + bflo(r0) + b0.x, 0.0f);
  float h1 = fmaxf(a1 * inv + bfhi(r0) + b0.y, 0.0f);
  float h2 = fmaxf(a2 * inv + bflo(r1) + b1.x, 0.0f);
  float h3 = fmaxf(a3 * inv + bfhi(r1) + b1.y, 0.0f);
  float h4 = fmaxf(a4 * inv + bflo(r2) + b2.x, 0.0f);
  float h5 = fmaxf(a5 * inv + bfhi(r2) + b2.y, 0.0f);

  if (!FINAL){
    unsigned int* O32 = (unsigned int*)hout + (long)node * 192;
    O32[l]       = f2bfu(h0) | (f2bfu(h1) << 16);
    O32[l + 64]  = f2bfu(h2) | (f2bfu(h3) << 16);
    O32[l + 128] = f2bfu(h4) | (f2bfu(h5) << 16);
  } else {
    float2* Y2 = (float2*)Y + (long)node * 192;
    Y2[l]       = make_float2(h0, h1);
    Y2[l + 64]  = make_float2(h2, h3);
    Y2[l + 128] = make_float2(h4, h5);
    const float4* WL4 = (const float4*)WL;
    float4 w0 = WL4[l], w1 = WL4[l + 64], w2 = WL4[l + 128];
    float s0 = h0 * w0.x + h1 * w0.z + h2 * w1.x + h3 * w1.z + h4 * w2.x + h5 * w2.z;
    float s1 = h0 * w0.y + h1 * w0.w + h2 * w1.y + h3 * w1.w + h4 * w2.y + h5 * w2.w;
    #pragma unroll
    for (int m = 32; m; m >>= 1){
      s0 += __shfl_xor(s0, m);
      s1 += __shfl_xor(s1, m);
    }
    if (l == 0){
      outp[(long)node * 2]     = 1.f / (1.f + expf(-(s0 + bl[0])));
      outp[(long)node * 2 + 1] = 1.f / (1.f + expf(-(s1 + bl[1])));
    }
  }
}

extern "C" void kernel_launch(void* const* d_in, const int* in_sizes, int n_in,
                              void* d_out, int out_size, void* d_ws, size_t ws_size,
                              hipStream_t stream) {
  const float* x      = (const float*)d_in[0];
  const int*   ei     = (const int*)d_in[1];
  const float* ew     = (const float*)d_in[2];
  const float* Wrel1  = (const float*)d_in[3];
  const float* brel1  = (const float*)d_in[4];
  const float* Wroot1 = (const float*)d_in[5];
  const float* Wrel2  = (const float*)d_in[6];
  const float* brel2  = (const float*)d_in[7];
  const float* Wroot2 = (const float*)d_in[8];
  const float* Wlin   = (const float*)d_in[9];
  const float* blin   = (const float*)d_in[10];

  const int NN = in_sizes[0] / 384;
  const int E  = in_sizes[2];
  const int* src = ei;
  const int* dst = ei + E;

  char* p = (char*)d_ws;
  auto carve = [&](size_t bytes) -> void* {
    void* r = (void*)p;
    p += (bytes + 255) & ~(size_t)255;
    return r;
  };
  int*   deg     = (int*)carve((size_t)NN * 4);
  int*   rowptr  = (int*)carve((size_t)(NN + 1) * 4);
  int*   cursor  = (int*)carve((size_t)NN * 4);
  int*   incl    = (int*)carve((size_t)NN * 4);
  int*   bsum    = (int*)carve(1024);
  int2*  csr     = (int2*)carve((size_t)E * 8);
  unsigned short* xb = (unsigned short*)carve((size_t)NN * 384 * 2);  // also reused as h
  unsigned short* Pb = (unsigned short*)carve((size_t)NN * 384 * 2);
  unsigned short* Rb = (unsigned short*)carve((size_t)NN * 384 * 2);
  unsigned short* WT1 = (unsigned short*)carve(384 * 384 * 2);
  unsigned short* WT2 = (unsigned short*)carve(384 * 384 * 2);
  unsigned short* WT3 = (unsigned short*)carve(384 * 384 * 2);
  unsigned short* WT4 = (unsigned short*)carve(384 * 384 * 2);

  float* out = (float*)d_out;
  float* Y   = out + (size_t)NN * 2;

  int nScanB = (NN + 1023) / 1024;

  hipMemsetAsync(deg, 0, (size_t)NN * 4, stream);
  k_cast_x<<<2048, 256, 0, stream>>>((const float4*)x, (uint2*)xb, NN * 96);
  dim3 wg(576, 4);
  k_castT_w4<<<wg, 256, 0, stream>>>(Wrel1, Wroot1, Wrel2, Wroot2, WT1, WT2, WT3, WT4);
  k_deg<<<1024, 256, 0, stream>>>(dst, deg, E);
  k_scan1<<<nScanB, 1024, 0, stream>>>(deg, incl, bsum, NN);
  k_scan2<<<1, 128, 0, stream>>>(bsum, nScanB);
  k_scan3<<<(NN + 255) / 256, 256, 0, stream>>>(incl, bsum, deg, rowptr, cursor, NN);
  k_fill<<<1024, 256, 0, stream>>>(src, dst, ew, cursor, csr, E);

  int nwg = 3 * ((NN + 127) / 128);
  int q = nwg >> 3, r = nwg & 7;
  int aggBlocks = (NN + 3) / 4;

  // layer 1: P = x@Wrel1, R = x@Wroot1; h = relu(mean(P) + R + b1) -> xb (x dead)
  k_gemm_dual<<<nwg, 256, 0, stream>>>(xb, WT1, WT2, Pb, Rb, NN, q, r);
  k_agg2<0><<<aggBlocks, 256, 0, stream>>>(Pb, Rb, brel1, rowptr, csr,
                                           xb, nullptr, nullptr, nullptr, nullptr, NN);

  // layer 2 + final linear/sigmoid fused into agg epilogue
  k_gemm_dual<<<nwg, 256, 0, stream>>>(xb, WT3, WT4, Pb, Rb, NN, q, r);
  k_agg2<1><<<aggBlocks, 256, 0, stream>>>(Pb, Rb, brel2, rowptr, csr,
                                           nullptr, Y, Wlin, blin, out, NN);
}